// Round 1
// baseline (606.215 us; speedup 1.0000x reference)
//
#include <hip/hip_runtime.h>
#include <stdint.h>

typedef _Float16 f16;
typedef _Float16 half8_t __attribute__((ext_vector_type(8)));
typedef _Float16 half4_t __attribute__((ext_vector_type(4)));
typedef float floatx4 __attribute__((ext_vector_type(4)));

#define B_  64
#define LA_ 512
#define LB_ 512
#define H_  768

// XOR swizzle on 16B chunks within a 128B row: kills the 16-way bank conflict
// of stride-128B ds_read_b128 fragment reads (T2). Same function on write & read.
static __device__ __forceinline__ int swz(int row, int byteInRow) {
    return row * 128 + (byteInRow ^ ((row & 7) << 4));
}

// ---------------------------------------------------------------------------
// K1: S = a . b^T * temp  ->  P = exp(S) (fp16), stored row-major AND transposed.
// grid (LB/128, LA/128, B), block 256 (4 waves, each 64x64 of the 128x128 tile)
// ---------------------------------------------------------------------------
__global__ __launch_bounds__(256) void qk_kernel(
    const float* __restrict__ Ag, const float* __restrict__ Bg,
    const int* __restrict__ maskA, const int* __restrict__ maskB,
    const float* __restrict__ temp_p,
    f16* __restrict__ P, f16* __restrict__ PT)
{
    __shared__ f16 As[128 * 64];
    __shared__ f16 Bs[128 * 64];
    __shared__ int mA[128];
    __shared__ int mB[128];

    const int t    = threadIdx.x;
    const int lane = t & 63;
    const int w    = t >> 6;
    const int wm   = w >> 1, wn = w & 1;
    const int jb   = blockIdx.x * 128;
    const int ib   = blockIdx.y * 128;
    const int b    = blockIdx.z;

    if (t < 128)      mA[t]       = maskA[b * LA_ + ib + t];
    else              mB[t - 128] = maskB[b * LB_ + jb + (t - 128)];

    floatx4 acc[4][4] = {};

    const int row  = t >> 1;
    const int half = t & 1;
    const float* srcA = Ag + (size_t)(b * LA_ + ib + row) * H_ + half * 32;
    const float* srcB = Bg + (size_t)(b * LB_ + jb + row) * H_ + half * 32;
    char* AsB = (char*)As;
    char* BsB = (char*)Bs;

    for (int kt = 0; kt < H_ / 64; ++kt) {
        // issue global loads before the barrier (hide latency under prior MFMA)
        floatx4 a4[8], b4[8];
        const floatx4* pa = (const floatx4*)(srcA + kt * 64);
        const floatx4* pb = (const floatx4*)(srcB + kt * 64);
        #pragma unroll
        for (int q = 0; q < 8; ++q) { a4[q] = pa[q]; b4[q] = pb[q]; }

        __syncthreads();   // previous tile fully consumed
        #pragma unroll
        for (int q = 0; q < 4; ++q) {
            half8_t ha, hb;
            #pragma unroll
            for (int e = 0; e < 8; ++e) {
                ha[e] = (f16)(a4[2 * q + (e >> 2)][e & 3]);
                hb[e] = (f16)(b4[2 * q + (e >> 2)][e & 3]);
            }
            const int off = swz(row, (half * 4 + q) * 16);
            *(half8_t*)(AsB + off) = ha;
            *(half8_t*)(BsB + off) = hb;
        }
        __syncthreads();

        #pragma unroll
        for (int ks = 0; ks < 2; ++ks) {
            half8_t af[4], bf[4];
            #pragma unroll
            for (int m = 0; m < 4; ++m) {
                const int r = wm * 64 + m * 16 + (lane & 15);
                af[m] = *(half8_t*)(AsB + swz(r, ks * 64 + ((lane >> 4) << 4)));
            }
            #pragma unroll
            for (int n = 0; n < 4; ++n) {
                const int r = wn * 64 + n * 16 + (lane & 15);
                bf[n] = *(half8_t*)(BsB + swz(r, ks * 64 + ((lane >> 4) << 4)));
            }
            #pragma unroll
            for (int m = 0; m < 4; ++m)
                #pragma unroll
                for (int n = 0; n < 4; ++n)
                    acc[m][n] = __builtin_amdgcn_mfma_f32_16x16x32_f16(
                        af[m], bf[n], acc[m][n], 0, 0, 0);
        }
    }

    // epilogue: P = mask ? exp(S*temp) : 0 ; store P (2B scalar, coalesces to
    // 32B runs across the 16 j-lanes) and PT (packed 8B: regs = 4 consecutive i)
    const float temp = *temp_p;
    #pragma unroll
    for (int m = 0; m < 4; ++m) {
        const int iloc0 = wm * 64 + m * 16 + ((lane >> 4) << 2);
        #pragma unroll
        for (int n = 0; n < 4; ++n) {
            const int jloc = wn * 64 + n * 16 + (lane & 15);
            const int vb = mB[jloc];
            half4_t hv;
            #pragma unroll
            for (int r = 0; r < 4; ++r) {
                const int iloc = iloc0 + r;
                const float s = acc[m][n][r] * temp;
                const float p = (mA[iloc] && vb) ? __expf(s) : 0.0f;
                hv[r] = (f16)p;
                P[(size_t)(b * LA_ + ib + iloc) * LB_ + jb + jloc] = hv[r];
            }
            *(half4_t*)(PT + (size_t)(b * LB_ + jb + jloc) * LA_ + ib + iloc0) = hv;
        }
    }
}

// ---------------------------------------------------------------------------
// K1b: softmax denominators = row sums of P (dir 0) / PT (dir 1). One wave per
// row, fully coalesced 16B loads, shfl-reduce, no atomics, no init needed.
// grid (512/64, B, 2), block 256
// ---------------------------------------------------------------------------
__global__ __launch_bounds__(256) void rowsum_kernel(
    const f16* __restrict__ P, const f16* __restrict__ PT,
    float* __restrict__ lrow, float* __restrict__ lcol)
{
    const int dir = blockIdx.z;
    const f16* src = dir ? PT : P;
    float*     dst = dir ? lcol : lrow;
    const int b  = blockIdx.y;
    const int rb = blockIdx.x * 64;
    const int wv = threadIdx.x >> 6, lane = threadIdx.x & 63;

    for (int r = wv; r < 64; r += 4) {
        const int row = rb + r;
        const half8_t raw = *(const half8_t*)(src + (size_t)(b * 512 + row) * 512 + lane * 8);
        float s = 0.f;
        #pragma unroll
        for (int e = 0; e < 8; ++e) s += (float)raw[e];
        #pragma unroll
        for (int off = 32; off > 0; off >>= 1) s += __shfl_down(s, off);
        if (lane == 0) dst[b * 512 + row] = s;
    }
}

// ---------------------------------------------------------------------------
// K2/K3 fused by blockIdx.z: feature = diag(1/l) * Pmat . V
//   dir 0: Pmat=P , V=b, l=lrow -> feature_a ; dir 1: Pmat=PT, V=a, l=lcol -> feature_b
// A-tile: fp16 from ws, swizzled LDS. V-tile: fp32->fp16 transpose-staged into
// [h][68] (pad 68 => fragment ds_read_b64 pairs conflict-free).
// grid (H/128, 512/128, 2*B), block 256
// ---------------------------------------------------------------------------
__global__ __launch_bounds__(256) void pv_kernel(
    const f16* __restrict__ Pmat, const f16* __restrict__ PTmat,
    const float* __restrict__ Ag, const float* __restrict__ Bg,
    const float* __restrict__ lrow, const float* __restrict__ lcol,
    float* __restrict__ out)
{
    __shared__ f16 As[128 * 64];
    __shared__ f16 Vs[128 * 68];
    __shared__ float Sc[128];

    const int t    = threadIdx.x;
    const int lane = t & 63;
    const int w    = t >> 6;
    const int wm   = w >> 1, wn = w & 1;
    const int hb   = blockIdx.x * 128;
    const int ib   = blockIdx.y * 128;
    const int z    = blockIdx.z;
    const int dir  = z >> 6;
    const int b    = z & 63;

    const f16*   Asrc = dir ? PTmat : Pmat;
    const float* Vsrc = dir ? Ag : Bg;
    const float* lsrc = dir ? lcol : lrow;
    float* o = out + (size_t)dir * ((size_t)B_ * LA_ * H_)
                   + (size_t)(b * 512 + ib) * H_ + hb;

    if (t < 128) {
        const float l = lsrc[b * 512 + ib + t];
        Sc[t] = (l > 0.f) ? 1.0f / l : 0.0f;
    }

    floatx4 acc[4][4] = {};

    const int arow = t >> 1, ahalf = t & 1;
    const f16* aptr = Asrc + (size_t)(b * 512 + ib + arow) * 512 + ahalf * 32;
    const int jg = t >> 4, hg = t & 15;          // V micro-tile: 4 j x 8 h
    const float* vptr = Vsrc + (size_t)(b * 512 + jg * 4) * H_ + hb + hg * 8;

    char* AsB = (char*)As;
    char* VsB = (char*)Vs;

    for (int kt = 0; kt < 512 / 64; ++kt) {
        half8_t araw[4];
        const half8_t* pa = (const half8_t*)(aptr + kt * 64);
        #pragma unroll
        for (int q = 0; q < 4; ++q) araw[q] = pa[q];

        floatx4 vraw[4][2];
        #pragma unroll
        for (int r = 0; r < 4; ++r) {
            const floatx4* pv = (const floatx4*)(vptr + (size_t)(kt * 64 + r) * H_);
            vraw[r][0] = pv[0];
            vraw[r][1] = pv[1];
        }

        __syncthreads();
        #pragma unroll
        for (int q = 0; q < 4; ++q)
            *(half8_t*)(AsB + swz(arow, (ahalf * 4 + q) * 16)) = araw[q];

        half8_t vt[4];
        #pragma unroll
        for (int r = 0; r < 4; ++r)
            #pragma unroll
            for (int e = 0; e < 8; ++e)
                vt[r][e] = (f16)(vraw[r][e >> 2][e & 3]);
        #pragma unroll
        for (int c = 0; c < 8; ++c) {
            half4_t wv;
            wv[0] = vt[0][c]; wv[1] = vt[1][c]; wv[2] = vt[2][c]; wv[3] = vt[3][c];
            *(half4_t*)(VsB + (hg * 8 + c) * 136 + jg * 8) = wv;
        }
        __syncthreads();

        #pragma unroll
        for (int ks = 0; ks < 2; ++ks) {
            half8_t af[4], vf[4];
            #pragma unroll
            for (int m = 0; m < 4; ++m) {
                const int r = wm * 64 + m * 16 + (lane & 15);
                af[m] = *(half8_t*)(AsB + swz(r, ks * 64 + ((lane >> 4) << 4)));
            }
            #pragma unroll
            for (int n = 0; n < 4; ++n) {
                const int hr = wn * 64 + n * 16 + (lane & 15);
                const int j  = ks * 32 + ((lane >> 4) << 3);
                char* base = VsB + hr * 136 + j * 2;
                half4_t lo = *(half4_t*)base;
                half4_t hi = *(half4_t*)(base + 8);
                vf[n] = __builtin_shufflevector(lo, hi, 0, 1, 2, 3, 4, 5, 6, 7);
            }
            #pragma unroll
            for (int m = 0; m < 4; ++m)
                #pragma unroll
                for (int n = 0; n < 4; ++n)
                    acc[m][n] = __builtin_amdgcn_mfma_f32_16x16x32_f16(
                        af[m], vf[n], acc[m][n], 0, 0, 0);
        }
    }

    #pragma unroll
    for (int m = 0; m < 4; ++m) {
        const int iloc0 = wm * 64 + m * 16 + ((lane >> 4) << 2);
        #pragma unroll
        for (int n = 0; n < 4; ++n) {
            const int hloc = wn * 64 + n * 16 + (lane & 15);
            #pragma unroll
            for (int r = 0; r < 4; ++r) {
                const int iloc = iloc0 + r;
                o[(size_t)iloc * H_ + hloc] = acc[m][n][r] * Sc[iloc];
            }
        }
    }
}

// ---------------------------------------------------------------------------
extern "C" void kernel_launch(void* const* d_in, const int* in_sizes, int n_in,
                              void* d_out, int out_size, void* d_ws, size_t ws_size,
                              hipStream_t stream)
{
    const float* a    = (const float*)d_in[0];
    const float* b    = (const float*)d_in[1];
    const int*   ma   = (const int*)d_in[2];
    const int*   mb   = (const int*)d_in[3];
    const float* temp = (const float*)d_in[4];
    float*       out  = (float*)d_out;

    // ws layout: P fp16 (33.5MB) | PT fp16 (33.5MB) | lrow (128KB) | lcol (128KB)
    const size_t WS_NEEDED = 67371008;
    if (ws_size < WS_NEEDED) return;  // clean failure signal instead of OOB writes

    char* ws   = (char*)d_ws;
    f16*  P    = (f16*)ws;
    f16*  PT   = (f16*)(ws + 33554432);
    float* lrow = (float*)(ws + 67108864);
    float* lcol = (float*)(ws + 67239936);

    qk_kernel<<<dim3(LB_ / 128, LA_ / 128, B_), 256, 0, stream>>>(
        a, b, ma, mb, temp, P, PT);
    rowsum_kernel<<<dim3(512 / 64, B_, 2), 256, 0, stream>>>(P, PT, lrow, lcol);
    pv_kernel<<<dim3(H_ / 128, 512 / 128, 2 * B_), 256, 0, stream>>>(
        P, PT, a, b, lrow, lcol, out);
}

// Round 5
// 542.203 us; speedup vs baseline: 1.1181x; 1.1181x over previous
//
#include <hip/hip_runtime.h>
#include <stdint.h>

typedef _Float16 f16;
typedef _Float16 half8_t __attribute__((ext_vector_type(8)));
typedef _Float16 half4_t __attribute__((ext_vector_type(4)));
typedef float floatx4 __attribute__((ext_vector_type(4)));

#define B_  64
#define LA_ 512
#define LB_ 512
#define H_  768

// XOR swizzle on 16B chunks within a 128B row: kills the 16-way bank conflict
// of stride-128B ds_read_b128 fragment reads (T2). Same function on write & read.
static __device__ __forceinline__ int swz(int row, int byteInRow) {
    return row * 128 + (byteInRow ^ ((row & 7) << 4));
}

// async global->LDS, 16B per lane. LDS dest must be wave-uniform base
// (HW adds lane*16); global address is per-lane (carries the swizzle).
static __device__ __forceinline__ void gload16(const void* g, void* l) {
    __builtin_amdgcn_global_load_lds(
        (const __attribute__((address_space(1))) unsigned int*)g,
        (__attribute__((address_space(3))) unsigned int*)l,
        16, 0, 0);
}

// ===========================================================================
// NEW PATH (fp16 operands in ws)
// ===========================================================================

// ---------------------------------------------------------------------------
// K0: convert a,b fp32 -> fp16 row-major (a16,b16) AND transposed [B][H][L]
// (aT,bT). grid (H/64, L/64, 2*B), block 256. 64x64 tile per block.
// ---------------------------------------------------------------------------
__global__ __launch_bounds__(256) void conv_kernel(
    const float* __restrict__ A, const float* __restrict__ Bm,
    f16* __restrict__ a16, f16* __restrict__ b16,
    f16* __restrict__ aT, f16* __restrict__ bT)
{
    __shared__ f16 Ts[64][68];   // pad 68: transposed column reads spread banks

    const int t  = threadIdx.x;
    const int hb = blockIdx.x * 64, lb = blockIdx.y * 64;
    const int z  = blockIdx.z, b = z >> 1, which = z & 1;

    const float* src = which ? Bm : A;
    f16* d  = which ? b16 : a16;
    f16* dT = which ? bT : aT;

    const int r = t >> 2, cs = (t & 3) * 16;
    const float* s = src + (size_t)(b * 512 + lb + r) * H_ + hb + cs;

    f16 hv[16];
    #pragma unroll
    for (int q = 0; q < 4; ++q) {
        floatx4 v = ((const floatx4*)s)[q];
        #pragma unroll
        for (int e = 0; e < 4; ++e) hv[q * 4 + e] = (f16)v[e];
    }

    // straight fp16 store (coalesced)
    f16* drow = d + (size_t)(b * 512 + lb + r) * H_ + hb + cs;
    {
        half8_t u0, u1;
        #pragma unroll
        for (int e = 0; e < 8; ++e) { u0[e] = hv[e]; u1[e] = hv[8 + e]; }
        *(half8_t*)drow = u0;
        *(half8_t*)(drow + 8) = u1;
    }

    // stage into LDS row-major, read back transposed
    #pragma unroll
    for (int e = 0; e < 16; ++e) Ts[r][cs + e] = hv[e];
    __syncthreads();

    const int h = t >> 2, ls = (t & 3) * 16;
    half8_t v0, v1;
    #pragma unroll
    for (int e = 0; e < 8; ++e) { v0[e] = Ts[ls + e][h]; v1[e] = Ts[ls + 8 + e][h]; }
    f16* dTrow = dT + ((size_t)b * H_ + hb + h) * 512 + lb + ls;
    *(half8_t*)dTrow = v0;
    *(half8_t*)(dTrow + 8) = v1;
}

// ---------------------------------------------------------------------------
// K1: S = a16 . b16^T * temp -> P = exp(S) fp16, row-major + transposed.
// 128x128 tile, BK=64, global_load_lds with pre-swizzled source.
// grid (LB/128, LA/128, B), block 256.
// ---------------------------------------------------------------------------
__global__ __launch_bounds__(256) void qk16_kernel(
    const f16* __restrict__ A16, const f16* __restrict__ B16,
    const int* __restrict__ maskA, const int* __restrict__ maskB,
    const float* __restrict__ temp_p,
    f16* __restrict__ P, f16* __restrict__ PT)
{
    __shared__ f16 As[128 * 64];
    __shared__ f16 Bs[128 * 64];
    __shared__ int mA[128];
    __shared__ int mB[128];

    const int t    = threadIdx.x;
    const int lane = t & 63;
    const int w    = t >> 6;
    const int wm   = w >> 1, wn = w & 1;
    const int jb   = blockIdx.x * 128;
    const int ib   = blockIdx.y * 128;
    const int b    = blockIdx.z;

    if (t < 128)      mA[t]       = maskA[b * LA_ + ib + t];
    else              mB[t - 128] = maskB[b * LB_ + jb + (t - 128)];

    floatx4 acc[4][4] = {};

    const f16* Ab = A16 + (size_t)(b * LA_ + ib) * H_;
    const f16* Bb = B16 + (size_t)(b * LB_ + jb) * H_;
    char* AsB = (char*)As;
    char* BsB = (char*)Bs;

    // per-thread staging geometry (loop-invariant): linear LDS offset o,
    // source fetches the inverse-swizzled byte so swz() reads are linear data.
    int srow[4], sbyt[4];
    #pragma unroll
    for (int q = 0; q < 4; ++q) {
        const int o = (q * 4 + w) * 1024 + lane * 16;
        srow[q] = o >> 7;
        sbyt[q] = (o & 127) ^ ((srow[q] & 7) << 4);
    }

    for (int kt = 0; kt < H_ / 64; ++kt) {
        #pragma unroll
        for (int q = 0; q < 4; ++q) {
            const int wc = q * 4 + w;
            const size_t go = (size_t)srow[q] * H_ + kt * 64 + (sbyt[q] >> 1);
            gload16(Ab + go, AsB + wc * 1024);
            gload16(Bb + go, BsB + wc * 1024);
        }
        __syncthreads();

        #pragma unroll
        for (int ks = 0; ks < 2; ++ks) {
            half8_t af[4], bf[4];
            #pragma unroll
            for (int m = 0; m < 4; ++m) {
                const int r = wm * 64 + m * 16 + (lane & 15);
                af[m] = *(half8_t*)(AsB + swz(r, ks * 64 + ((lane >> 4) << 4)));
            }
            #pragma unroll
            for (int n = 0; n < 4; ++n) {
                const int r = wn * 64 + n * 16 + (lane & 15);
                bf[n] = *(half8_t*)(BsB + swz(r, ks * 64 + ((lane >> 4) << 4)));
            }
            #pragma unroll
            for (int m = 0; m < 4; ++m)
                #pragma unroll
                for (int n = 0; n < 4; ++n)
                    acc[m][n] = __builtin_amdgcn_mfma_f32_16x16x32_f16(
                        af[m], bf[n], acc[m][n], 0, 0, 0);
        }
        __syncthreads();
    }

    const float temp = *temp_p;
    #pragma unroll
    for (int m = 0; m < 4; ++m) {
        const int iloc0 = wm * 64 + m * 16 + ((lane >> 4) << 2);
        #pragma unroll
        for (int n = 0; n < 4; ++n) {
            const int jloc = wn * 64 + n * 16 + (lane & 15);
            const int vb = mB[jloc];
            half4_t hv;
            #pragma unroll
            for (int r = 0; r < 4; ++r) {
                const int iloc = iloc0 + r;
                const float s = acc[m][n][r] * temp;
                const float p = (mA[iloc] && vb) ? __expf(s) : 0.0f;
                hv[r] = (f16)p;
                P[(size_t)(b * LA_ + ib + iloc) * LB_ + jb + jloc] = hv[r];
            }
            *(half4_t*)(PT + (size_t)(b * LB_ + jb + jloc) * LA_ + ib + iloc0) = hv;
        }
    }
}

// ---------------------------------------------------------------------------
// K1b: softmax denominators = row sums of P / PT. One wave per row.
// grid (512/64, B, 2), block 256.
// ---------------------------------------------------------------------------
__global__ __launch_bounds__(256) void rowsum_kernel(
    const f16* __restrict__ P, const f16* __restrict__ PT,
    float* __restrict__ lrow, float* __restrict__ lcol)
{
    const int dir = blockIdx.z;
    const f16* src = dir ? PT : P;
    float*     dst = dir ? lcol : lrow;
    const int b  = blockIdx.y;
    const int rb = blockIdx.x * 64;
    const int wv = threadIdx.x >> 6, lane = threadIdx.x & 63;

    for (int r = wv; r < 64; r += 4) {
        const int row = rb + r;
        const half8_t raw = *(const half8_t*)(src + (size_t)(b * 512 + row) * 512 + lane * 8);
        float s = 0.f;
        #pragma unroll
        for (int e = 0; e < 8; ++e) s += (float)raw[e];
        #pragma unroll
        for (int off = 32; off > 0; off >>= 1) s += __shfl_down(s, off);
        if (lane == 0) dst[b * 512 + row] = s;
    }
}

// ---------------------------------------------------------------------------
// K2: feature = diag(1/l) * Pmat . V, both operands fp16 row-major, both
// staged via global_load_lds. dir0: P . bT-rows -> feature_a; dir1: PT . aT.
// grid (H/128, 512/128, 2*B), block 256.
// ---------------------------------------------------------------------------
__global__ __launch_bounds__(256) void pv16_kernel(
    const f16* __restrict__ P, const f16* __restrict__ PT,
    const f16* __restrict__ aT, const f16* __restrict__ bT,
    const float* __restrict__ lrow, const float* __restrict__ lcol,
    float* __restrict__ out)
{
    __shared__ f16 As[128 * 64];
    __shared__ f16 Vs[128 * 64];
    __shared__ float Sc[128];

    const int t    = threadIdx.x;
    const int lane = t & 63;
    const int w    = t >> 6;
    const int wm   = w >> 1, wn = w & 1;
    const int hb   = blockIdx.x * 128;
    const int ib   = blockIdx.y * 128;
    const int z    = blockIdx.z;
    const int dir  = z >> 6;
    const int b    = z & 63;

    const f16* Ab = (dir ? PT : P) + (size_t)(b * 512 + ib) * 512;
    const f16* Vb = (dir ? aT : bT) + ((size_t)b * H_ + hb) * 512;
    const float* lsrc = dir ? lcol : lrow;
    float* o = out + (size_t)dir * ((size_t)B_ * LA_ * H_)
                   + (size_t)(b * 512 + ib) * H_ + hb;

    if (t < 128) {
        const float l = lsrc[b * 512 + ib + t];
        Sc[t] = (l > 0.f) ? 1.0f / l : 0.0f;
    }

    floatx4 acc[4][4] = {};
    char* AsB = (char*)As;
    char* VsB = (char*)Vs;

    int srow[4], sbyt[4];
    #pragma unroll
    for (int q = 0; q < 4; ++q) {
        const int o2 = (q * 4 + w) * 1024 + lane * 16;
        srow[q] = o2 >> 7;
        sbyt[q] = (o2 & 127) ^ ((srow[q] & 7) << 4);
    }

    for (int kt = 0; kt < 512 / 64; ++kt) {
        #pragma unroll
        for (int q = 0; q < 4; ++q) {
            const int wc = q * 4 + w;
            const size_t go = (size_t)srow[q] * 512 + kt * 64 + (sbyt[q] >> 1);
            gload16(Ab + go, AsB + wc * 1024);
            gload16(Vb + go, VsB + wc * 1024);
        }
        __syncthreads();

        #pragma unroll
        for (int ks = 0; ks < 2; ++ks) {
            half8_t af[4], vf[4];
            #pragma unroll
            for (int m = 0; m < 4; ++m) {
                const int r = wm * 64 + m * 16 + (lane & 15);
                af[m] = *(half8_t*)(AsB + swz(r, ks * 64 + ((lane >> 4) << 4)));
            }
            #pragma unroll
            for (int n = 0; n < 4; ++n) {
                const int r = wn * 64 + n * 16 + (lane & 15);
                vf[n] = *(half8_t*)(VsB + swz(r, ks * 64 + ((lane >> 4) << 4)));
            }
            #pragma unroll
            for (int m = 0; m < 4; ++m)
                #pragma unroll
                for (int n = 0; n < 4; ++n)
                    acc[m][n] = __builtin_amdgcn_mfma_f32_16x16x32_f16(
                        af[m], vf[n], acc[m][n], 0, 0, 0);
        }
        __syncthreads();
    }

    #pragma unroll
    for (int m = 0; m < 4; ++m) {
        const int iloc0 = wm * 64 + m * 16 + ((lane >> 4) << 2);
        #pragma unroll
        for (int n = 0; n < 4; ++n) {
            const int hloc = wn * 64 + n * 16 + (lane & 15);
            #pragma unroll
            for (int r = 0; r < 4; ++r) {
                const int iloc = iloc0 + r;
                o[(size_t)iloc * H_ + hloc] = acc[m][n][r] * Sc[iloc];
            }
        }
    }
}

// ===========================================================================
// FALLBACK PATH (round-1 kernels, known-passing) — used if ws is too small
// ===========================================================================

__global__ __launch_bounds__(256) void qk_kernel(
    const float* __restrict__ Ag, const float* __restrict__ Bg,
    const int* __restrict__ maskA, const int* __restrict__ maskB,
    const float* __restrict__ temp_p,
    f16* __restrict__ P, f16* __restrict__ PT)
{
    __shared__ f16 As[128 * 64];
    __shared__ f16 Bs[128 * 64];
    __shared__ int mA[128];
    __shared__ int mB[128];

    const int t    = threadIdx.x;
    const int lane = t & 63;
    const int w    = t >> 6;
    const int wm   = w >> 1, wn = w & 1;
    const int jb   = blockIdx.x * 128;
    const int ib   = blockIdx.y * 128;
    const int b    = blockIdx.z;

    if (t < 128)      mA[t]       = maskA[b * LA_ + ib + t];
    else              mB[t - 128] = maskB[b * LB_ + jb + (t - 128)];

    floatx4 acc[4][4] = {};

    const int row  = t >> 1;
    const int half = t & 1;
    const float* srcA = Ag + (size_t)(b * LA_ + ib + row) * H_ + half * 32;
    const float* srcB = Bg + (size_t)(b * LB_ + jb + row) * H_ + half * 32;
    char* AsB = (char*)As;
    char* BsB = (char*)Bs;

    for (int kt = 0; kt < H_ / 64; ++kt) {
        floatx4 a4[8], b4[8];
        const floatx4* pa = (const floatx4*)(srcA + kt * 64);
        const floatx4* pb = (const floatx4*)(srcB + kt * 64);
        #pragma unroll
        for (int q = 0; q < 8; ++q) { a4[q] = pa[q]; b4[q] = pb[q]; }

        __syncthreads();
        #pragma unroll
        for (int q = 0; q < 4; ++q) {
            half8_t ha, hb;
            #pragma unroll
            for (int e = 0; e < 8; ++e) {
                ha[e] = (f16)(a4[2 * q + (e >> 2)][e & 3]);
                hb[e] = (f16)(b4[2 * q + (e >> 2)][e & 3]);
            }
            const int off = swz(row, (half * 4 + q) * 16);
            *(half8_t*)(AsB + off) = ha;
            *(half8_t*)(BsB + off) = hb;
        }
        __syncthreads();

        #pragma unroll
        for (int ks = 0; ks < 2; ++ks) {
            half8_t af[4], bf[4];
            #pragma unroll
            for (int m = 0; m < 4; ++m) {
                const int r = wm * 64 + m * 16 + (lane & 15);
                af[m] = *(half8_t*)(AsB + swz(r, ks * 64 + ((lane >> 4) << 4)));
            }
            #pragma unroll
            for (int n = 0; n < 4; ++n) {
                const int r = wn * 64 + n * 16 + (lane & 15);
                bf[n] = *(half8_t*)(BsB + swz(r, ks * 64 + ((lane >> 4) << 4)));
            }
            #pragma unroll
            for (int m = 0; m < 4; ++m)
                #pragma unroll
                for (int n = 0; n < 4; ++n)
                    acc[m][n] = __builtin_amdgcn_mfma_f32_16x16x32_f16(
                        af[m], bf[n], acc[m][n], 0, 0, 0);
        }
    }

    const float temp = *temp_p;
    #pragma unroll
    for (int m = 0; m < 4; ++m) {
        const int iloc0 = wm * 64 + m * 16 + ((lane >> 4) << 2);
        #pragma unroll
        for (int n = 0; n < 4; ++n) {
            const int jloc = wn * 64 + n * 16 + (lane & 15);
            const int vb = mB[jloc];
            half4_t hv;
            #pragma unroll
            for (int r = 0; r < 4; ++r) {
                const int iloc = iloc0 + r;
                const float s = acc[m][n][r] * temp;
                const float p = (mA[iloc] && vb) ? __expf(s) : 0.0f;
                hv[r] = (f16)p;
                P[(size_t)(b * LA_ + ib + iloc) * LB_ + jb + jloc] = hv[r];
            }
            *(half4_t*)(PT + (size_t)(b * LB_ + jb + jloc) * LA_ + ib + iloc0) = hv;
        }
    }
}

__global__ __launch_bounds__(256) void pv_kernel(
    const f16* __restrict__ Pmat, const f16* __restrict__ PTmat,
    const float* __restrict__ Ag, const float* __restrict__ Bg,
    const float* __restrict__ lrow, const float* __restrict__ lcol,
    float* __restrict__ out)
{
    __shared__ f16 As[128 * 64];
    __shared__ f16 Vs[128 * 68];
    __shared__ float Sc[128];

    const int t    = threadIdx.x;
    const int lane = t & 63;
    const int w    = t >> 6;
    const int wm   = w >> 1, wn = w & 1;
    const int hb   = blockIdx.x * 128;
    const int ib   = blockIdx.y * 128;
    const int z    = blockIdx.z;
    const int dir  = z >> 6;
    const int b    = z & 63;

    const f16*   Asrc = dir ? PTmat : Pmat;
    const float* Vsrc = dir ? Ag : Bg;
    const float* lsrc = dir ? lcol : lrow;
    float* o = out + (size_t)dir * ((size_t)B_ * LA_ * H_)
                   + (size_t)(b * 512 + ib) * H_ + hb;

    if (t < 128) {
        const float l = lsrc[b * 512 + ib + t];
        Sc[t] = (l > 0.f) ? 1.0f / l : 0.0f;
    }

    floatx4 acc[4][4] = {};

    const int arow = t >> 1, ahalf = t & 1;
    const f16* aptr = Asrc + (size_t)(b * 512 + ib + arow) * 512 + ahalf * 32;
    const int jg = t >> 4, hg = t & 15;
    const float* vptr = Vsrc + (size_t)(b * 512 + jg * 4) * H_ + hb + hg * 8;

    char* AsB = (char*)As;
    char* VsB = (char*)Vs;

    for (int kt = 0; kt < 512 / 64; ++kt) {
        half8_t araw[4];
        const half8_t* pa = (const half8_t*)(aptr + kt * 64);
        #pragma unroll
        for (int q = 0; q < 4; ++q) araw[q] = pa[q];

        floatx4 vraw[4][2];
        #pragma unroll
        for (int r = 0; r < 4; ++r) {
            const floatx4* pv = (const floatx4*)(vptr + (size_t)(kt * 64 + r) * H_);
            vraw[r][0] = pv[0];
            vraw[r][1] = pv[1];
        }

        __syncthreads();
        #pragma unroll
        for (int q = 0; q < 4; ++q)
            *(half8_t*)(AsB + swz(arow, (ahalf * 4 + q) * 16)) = araw[q];

        half8_t vt[4];
        #pragma unroll
        for (int r = 0; r < 4; ++r)
            #pragma unroll
            for (int e = 0; e < 8; ++e)
                vt[r][e] = (f16)(vraw[r][e >> 2][e & 3]);
        #pragma unroll
        for (int c = 0; c < 8; ++c) {
            half4_t wv;
            wv[0] = vt[0][c]; wv[1] = vt[1][c]; wv[2] = vt[2][c]; wv[3] = vt[3][c];
            *(half4_t*)(VsB + (hg * 8 + c) * 136 + jg * 8) = wv;
        }
        __syncthreads();

        #pragma unroll
        for (int ks = 0; ks < 2; ++ks) {
            half8_t af[4], vf[4];
            #pragma unroll
            for (int m = 0; m < 4; ++m) {
                const int r = wm * 64 + m * 16 + (lane & 15);
                af[m] = *(half8_t*)(AsB + swz(r, ks * 64 + ((lane >> 4) << 4)));
            }
            #pragma unroll
            for (int n = 0; n < 4; ++n) {
                const int hr = wn * 64 + n * 16 + (lane & 15);
                const int j  = ks * 32 + ((lane >> 4) << 3);
                char* base = VsB + hr * 136 + j * 2;
                half4_t lo = *(half4_t*)base;
                half4_t hi = *(half4_t*)(base + 8);
                vf[n] = __builtin_shufflevector(lo, hi, 0, 1, 2, 3, 4, 5, 6, 7);
            }
            #pragma unroll
            for (int m = 0; m < 4; ++m)
                #pragma unroll
                for (int n = 0; n < 4; ++n)
                    acc[m][n] = __builtin_amdgcn_mfma_f32_16x16x32_f16(
                        af[m], vf[n], acc[m][n], 0, 0, 0);
        }
    }

    #pragma unroll
    for (int m = 0; m < 4; ++m) {
        const int iloc0 = wm * 64 + m * 16 + ((lane >> 4) << 2);
        #pragma unroll
        for (int n = 0; n < 4; ++n) {
            const int hloc = wn * 64 + n * 16 + (lane & 15);
            #pragma unroll
            for (int r = 0; r < 4; ++r) {
                const int iloc = iloc0 + r;
                o[(size_t)iloc * H_ + hloc] = acc[m][n][r] * Sc[iloc];
            }
        }
    }
}

// ---------------------------------------------------------------------------
extern "C" void kernel_launch(void* const* d_in, const int* in_sizes, int n_in,
                              void* d_out, int out_size, void* d_ws, size_t ws_size,
                              hipStream_t stream)
{
    const float* a    = (const float*)d_in[0];
    const float* b    = (const float*)d_in[1];
    const int*   ma   = (const int*)d_in[2];
    const int*   mb   = (const int*)d_in[3];
    const float* temp = (const float*)d_in[4];
    float*       out  = (float*)d_out;
    char*        ws   = (char*)d_ws;

    // new-path ws layout:
    // a16 50331648 | b16 50331648 | aT 50331648 | bT 50331648 |
    // P 33554432 | PT 33554432 | lrow 131072 | lcol 131072
    const size_t NEW_NEED = 268697600;
    const size_t OLD_NEED = 67371008;

    if (ws_size >= NEW_NEED) {
        f16*   a16  = (f16*)(ws);
        f16*   b16  = (f16*)(ws + 50331648);
        f16*   aT   = (f16*)(ws + 100663296);
        f16*   bT   = (f16*)(ws + 150994944);
        f16*   P    = (f16*)(ws + 201326592);
        f16*   PT   = (f16*)(ws + 234881024);
        float* lrow = (float*)(ws + 268435456);
        float* lcol = (float*)(ws + 268566528);

        conv_kernel<<<dim3(H_ / 64, 512 / 64, 2 * B_), 256, 0, stream>>>(
            a, b, a16, b16, aT, bT);
        qk16_kernel<<<dim3(LB_ / 128, LA_ / 128, B_), 256, 0, stream>>>(
            a16, b16, ma, mb, temp, P, PT);
        rowsum_kernel<<<dim3(512 / 64, B_, 2), 256, 0, stream>>>(P, PT, lrow, lcol);
        pv16_kernel<<<dim3(H_ / 128, 512 / 128, 2 * B_), 256, 0, stream>>>(
            P, PT, aT, bT, lrow, lcol, out);
    } else if (ws_size >= OLD_NEED) {
        f16*   P    = (f16*)(ws);
        f16*   PT   = (f16*)(ws + 33554432);
        float* lrow = (float*)(ws + 67108864);
        float* lcol = (float*)(ws + 67239936);

        qk_kernel<<<dim3(LB_ / 128, LA_ / 128, B_), 256, 0, stream>>>(
            a, b, ma, mb, temp, P, PT);
        rowsum_kernel<<<dim3(512 / 64, B_, 2), 256, 0, stream>>>(P, PT, lrow, lcol);
        pv_kernel<<<dim3(H_ / 128, 512 / 128, 2 * B_), 256, 0, stream>>>(
            P, PT, a, b, lrow, lcol, out);
    }
}

// Round 6
// 532.387 us; speedup vs baseline: 1.1387x; 1.0184x over previous
//
#include <hip/hip_runtime.h>
#include <stdint.h>

typedef _Float16 f16;
typedef _Float16 half8_t __attribute__((ext_vector_type(8)));
typedef _Float16 half4_t __attribute__((ext_vector_type(4)));
typedef float floatx4 __attribute__((ext_vector_type(4)));

#define B_  64
#define LA_ 512
#define LB_ 512
#define H_  768

// XOR swizzle on 16B chunks within a 128B row (T2). Same involution on the
// pre-swizzled global source and the ds_read addresses (rule #21).
static __device__ __forceinline__ int swz(int row, int byteInRow) {
    return row * 128 + (byteInRow ^ ((row & 7) << 4));
}

// async global->LDS, 16B/lane. LDS dest wave-uniform base + lane*16 (m104);
// per-lane global address carries the inverse swizzle.
static __device__ __forceinline__ void gload16(const void* g, void* l) {
    __builtin_amdgcn_global_load_lds(
        (const __attribute__((address_space(1))) unsigned int*)g,
        (__attribute__((address_space(3))) unsigned int*)l,
        16, 0, 0);
}

// ---------------------------------------------------------------------------
// K0: convert a,b fp32 -> fp16 row-major (a16,b16) AND transposed [B][H][L]
// (aT,bT). grid (H/64, L/64, 2*B), block 256. Pure streaming, no reuse -> no
// XCD swizzle (T1 transfer: null on streaming ops).
// ---------------------------------------------------------------------------
__global__ __launch_bounds__(256) void conv_kernel(
    const float* __restrict__ A, const float* __restrict__ Bm,
    f16* __restrict__ a16, f16* __restrict__ b16,
    f16* __restrict__ aT, f16* __restrict__ bT)
{
    __shared__ f16 Ts[64][68];   // pad 68: transposed column reads spread banks

    const int t  = threadIdx.x;
    const int hb = blockIdx.x * 64, lb = blockIdx.y * 64;
    const int z  = blockIdx.z, b = z >> 1, which = z & 1;

    const float* src = which ? Bm : A;
    f16* d  = which ? b16 : a16;
    f16* dT = which ? bT : aT;

    const int r = t >> 2, cs = (t & 3) * 16;
    const float* s = src + (size_t)(b * 512 + lb + r) * H_ + hb + cs;

    f16 hv[16];
    #pragma unroll
    for (int q = 0; q < 4; ++q) {
        floatx4 v = ((const floatx4*)s)[q];
        #pragma unroll
        for (int e = 0; e < 4; ++e) hv[q * 4 + e] = (f16)v[e];
    }

    f16* drow = d + (size_t)(b * 512 + lb + r) * H_ + hb + cs;
    {
        half8_t u0, u1;
        #pragma unroll
        for (int e = 0; e < 8; ++e) { u0[e] = hv[e]; u1[e] = hv[8 + e]; }
        *(half8_t*)drow = u0;
        *(half8_t*)(drow + 8) = u1;
    }

    #pragma unroll
    for (int e = 0; e < 16; ++e) Ts[r][cs + e] = hv[e];
    __syncthreads();

    const int h = t >> 2, ls = (t & 3) * 16;
    half8_t v0, v1;
    #pragma unroll
    for (int e = 0; e < 8; ++e) { v0[e] = Ts[ls + e][h]; v1[e] = Ts[ls + 8 + e][h]; }
    f16* dTrow = dT + ((size_t)b * H_ + hb + h) * 512 + lb + ls;
    *(half8_t*)dTrow = v0;
    *(half8_t*)(dTrow + 8) = v1;
}

// ---------------------------------------------------------------------------
// K1: S = a16 . b16^T * temp -> P = exp(S) fp16, row-major + transposed.
// 128x128 tile, BK=64, DOUBLE-BUFFERED global_load_lds prefetch (one barrier
// per K-step), flat grid + bijective XCD swizzle (nwg=1024, 1024%8==0).
// ---------------------------------------------------------------------------
__global__ __launch_bounds__(256) void qk16_kernel(
    const f16* __restrict__ A16, const f16* __restrict__ B16,
    const int* __restrict__ maskA, const int* __restrict__ maskB,
    const float* __restrict__ temp_p,
    f16* __restrict__ P, f16* __restrict__ PT)
{
    __shared__ f16 As[2][128 * 64];
    __shared__ f16 Bs[2][128 * 64];
    __shared__ int mA[128];
    __shared__ int mB[128];

    const int t    = threadIdx.x;
    const int lane = t & 63;
    const int w    = t >> 6;
    const int wm   = w >> 1, wn = w & 1;

    // XCD swizzle: XCD k owns contiguous ids [k*128,(k+1)*128) = 8 full
    // b-slices (a16/b16 slabs 1.5 MB/slice << 4 MB L2).
    int id = (int)blockIdx.x;
    id = (id & 7) * 128 + (id >> 3);
    const int jb = (id & 3) * 128;
    const int ib = ((id >> 2) & 3) * 128;
    const int b  = id >> 4;

    if (t < 128)      mA[t]       = maskA[b * LA_ + ib + t];
    else              mB[t - 128] = maskB[b * LB_ + jb + (t - 128)];

    floatx4 acc[4][4] = {};

    const f16* Ab = A16 + (size_t)(b * LA_ + ib) * H_;
    const f16* Bb = B16 + (size_t)(b * LB_ + jb) * H_;

    // staging geometry: linear LDS offset o, source pre-applies inverse swizzle
    int srow[4], sbyt[4];
    #pragma unroll
    for (int q = 0; q < 4; ++q) {
        const int o = (q * 4 + w) * 1024 + lane * 16;
        srow[q] = o >> 7;
        sbyt[q] = (o & 127) ^ ((srow[q] & 7) << 4);
    }

    #define QK_STAGE(bufi, kt)                                            \
        _Pragma("unroll")                                                 \
        for (int q = 0; q < 4; ++q) {                                     \
            const int wc = q * 4 + w;                                     \
            const size_t go = (size_t)srow[q] * H_ + (kt) * 64 + (sbyt[q] >> 1); \
            gload16(Ab + go, (char*)As[bufi] + wc * 1024);                \
            gload16(Bb + go, (char*)Bs[bufi] + wc * 1024);                \
        }

    QK_STAGE(0, 0);
    int cur = 0;

    for (int kt = 0; kt < H_ / 64; ++kt) {
        __syncthreads();                 // drains stage(kt) + orders LDS reuse
        if (kt + 1 < H_ / 64) { QK_STAGE(cur ^ 1, kt + 1); }  // fly under MFMA

        char* AsB = (char*)As[cur];
        char* BsB = (char*)Bs[cur];
        #pragma unroll
        for (int ks = 0; ks < 2; ++ks) {
            half8_t af[4], bf[4];
            #pragma unroll
            for (int m = 0; m < 4; ++m) {
                const int r = wm * 64 + m * 16 + (lane & 15);
                af[m] = *(half8_t*)(AsB + swz(r, ks * 64 + ((lane >> 4) << 4)));
            }
            #pragma unroll
            for (int n = 0; n < 4; ++n) {
                const int r = wn * 64 + n * 16 + (lane & 15);
                bf[n] = *(half8_t*)(BsB + swz(r, ks * 64 + ((lane >> 4) << 4)));
            }
            #pragma unroll
            for (int m = 0; m < 4; ++m)
                #pragma unroll
                for (int n = 0; n < 4; ++n)
                    acc[m][n] = __builtin_amdgcn_mfma_f32_16x16x32_f16(
                        af[m], bf[n], acc[m][n], 0, 0, 0);
        }
        cur ^= 1;
    }
    #undef QK_STAGE

    const float temp = *temp_p;
    #pragma unroll
    for (int m = 0; m < 4; ++m) {
        const int iloc0 = wm * 64 + m * 16 + ((lane >> 4) << 2);
        #pragma unroll
        for (int n = 0; n < 4; ++n) {
            const int jloc = wn * 64 + n * 16 + (lane & 15);
            const int vb = mB[jloc];
            half4_t hv;
            #pragma unroll
            for (int r = 0; r < 4; ++r) {
                const int iloc = iloc0 + r;
                const float s = acc[m][n][r] * temp;
                const float p = (mA[iloc] && vb) ? __expf(s) : 0.0f;
                hv[r] = (f16)p;
                P[(size_t)(b * LA_ + ib + iloc) * LB_ + jb + jloc] = hv[r];
            }
            *(half4_t*)(PT + (size_t)(b * LB_ + jb + jloc) * LA_ + ib + iloc0) = hv;
        }
    }
}

// ---------------------------------------------------------------------------
// K1b: softmax denominators = row sums of P / PT (L3-resident). One wave/row.
// ---------------------------------------------------------------------------
__global__ __launch_bounds__(256) void rowsum_kernel(
    const f16* __restrict__ P, const f16* __restrict__ PT,
    float* __restrict__ lrow, float* __restrict__ lcol)
{
    const int dir = blockIdx.z;
    const f16* src = dir ? PT : P;
    float*     dst = dir ? lcol : lrow;
    const int b  = blockIdx.y;
    const int rb = blockIdx.x * 64;
    const int wv = threadIdx.x >> 6, lane = threadIdx.x & 63;

    for (int r = wv; r < 64; r += 4) {
        const int row = rb + r;
        const half8_t raw = *(const half8_t*)(src + (size_t)(b * 512 + row) * 512 + lane * 8);
        float s = 0.f;
        #pragma unroll
        for (int e = 0; e < 8; ++e) s += (float)raw[e];
        #pragma unroll
        for (int off = 32; off > 0; off >>= 1) s += __shfl_down(s, off);
        if (lane == 0) dst[b * 512 + row] = s;
    }
}

// ---------------------------------------------------------------------------
// K2: feature = diag(1/l) * Pmat . V, fp16 x fp16, double-buffered prefetch,
// flat grid + bijective XCD swizzle (nwg=3072). dir0: P.bT -> feature_a;
// dir1: PT.aT -> feature_b.
// ---------------------------------------------------------------------------
__global__ __launch_bounds__(256) void pv16_kernel(
    const f16* __restrict__ P, const f16* __restrict__ PT,
    const f16* __restrict__ aT, const f16* __restrict__ bT,
    const float* __restrict__ lrow, const float* __restrict__ lcol,
    float* __restrict__ out)
{
    __shared__ f16 As[2][128 * 64];
    __shared__ f16 Vs[2][128 * 64];
    __shared__ float Sc[128];

    const int t    = threadIdx.x;
    const int lane = t & 63;
    const int w    = t >> 6;
    const int wm   = w >> 1, wn = w & 1;

    // XCD swizzle: XCD k owns ids [k*384,(k+1)*384) = 16 (dir,b)-slices;
    // per-slice P-slab 524KB + V-slab 786KB fits one XCD L2.
    int id = (int)blockIdx.x;
    id = (id & 7) * 384 + (id >> 3);
    const int hb = (id % 6) * 128;
    const int rem = id / 6;
    const int ib = (rem & 3) * 128;
    const int z  = rem >> 2;
    const int dir = z >> 6;
    const int b   = z & 63;

    const f16* Ab = (dir ? PT : P) + (size_t)(b * 512 + ib) * 512;
    const f16* Vb = (dir ? aT : bT) + ((size_t)b * H_ + hb) * 512;
    const float* lsrc = dir ? lcol : lrow;
    float* o = out + (size_t)dir * ((size_t)B_ * LA_ * H_)
                   + (size_t)(b * 512 + ib) * H_ + hb;

    if (t < 128) {
        const float l = lsrc[b * 512 + ib + t];
        Sc[t] = (l > 0.f) ? 1.0f / l : 0.0f;
    }

    floatx4 acc[4][4] = {};

    int srow[4], sbyt[4];
    #pragma unroll
    for (int q = 0; q < 4; ++q) {
        const int o2 = (q * 4 + w) * 1024 + lane * 16;
        srow[q] = o2 >> 7;
        sbyt[q] = (o2 & 127) ^ ((srow[q] & 7) << 4);
    }

    #define PV_STAGE(bufi, kt)                                            \
        _Pragma("unroll")                                                 \
        for (int q = 0; q < 4; ++q) {                                     \
            const int wc = q * 4 + w;                                     \
            const size_t go = (size_t)srow[q] * 512 + (kt) * 64 + (sbyt[q] >> 1); \
            gload16(Ab + go, (char*)As[bufi] + wc * 1024);                \
            gload16(Vb + go, (char*)Vs[bufi] + wc * 1024);                \
        }

    PV_STAGE(0, 0);
    int cur = 0;

    for (int kt = 0; kt < 512 / 64; ++kt) {
        __syncthreads();
        if (kt + 1 < 512 / 64) { PV_STAGE(cur ^ 1, kt + 1); }

        char* AsB = (char*)As[cur];
        char* VsB = (char*)Vs[cur];
        #pragma unroll
        for (int ks = 0; ks < 2; ++ks) {
            half8_t af[4], vf[4];
            #pragma unroll
            for (int m = 0; m < 4; ++m) {
                const int r = wm * 64 + m * 16 + (lane & 15);
                af[m] = *(half8_t*)(AsB + swz(r, ks * 64 + ((lane >> 4) << 4)));
            }
            #pragma unroll
            for (int n = 0; n < 4; ++n) {
                const int r = wn * 64 + n * 16 + (lane & 15);
                vf[n] = *(half8_t*)(VsB + swz(r, ks * 64 + ((lane >> 4) << 4)));
            }
            #pragma unroll
            for (int m = 0; m < 4; ++m)
                #pragma unroll
                for (int n = 0; n < 4; ++n)
                    acc[m][n] = __builtin_amdgcn_mfma_f32_16x16x32_f16(
                        af[m], vf[n], acc[m][n], 0, 0, 0);
        }
        cur ^= 1;
    }
    #undef PV_STAGE

    #pragma unroll
    for (int m = 0; m < 4; ++m) {
        const int iloc0 = wm * 64 + m * 16 + ((lane >> 4) << 2);
        #pragma unroll
        for (int n = 0; n < 4; ++n) {
            const int hloc = wn * 64 + n * 16 + (lane & 15);
            #pragma unroll
            for (int r = 0; r < 4; ++r) {
                const int iloc = iloc0 + r;
                o[(size_t)iloc * H_ + hloc] = acc[m][n][r] * Sc[iloc];
            }
        }
    }
}

// ---------------------------------------------------------------------------
extern "C" void kernel_launch(void* const* d_in, const int* in_sizes, int n_in,
                              void* d_out, int out_size, void* d_ws, size_t ws_size,
                              hipStream_t stream)
{
    const float* a    = (const float*)d_in[0];
    const float* b    = (const float*)d_in[1];
    const int*   ma   = (const int*)d_in[2];
    const int*   mb   = (const int*)d_in[3];
    const float* temp = (const float*)d_in[4];
    float*       out  = (float*)d_out;
    char*        ws   = (char*)d_ws;

    // ws layout: a16 | b16 | aT | bT | P | PT | lrow | lcol
    const size_t NEW_NEED = 268697600;
    if (ws_size < NEW_NEED) return;   // proven >= on this harness (round 5 ran)

    f16*   a16  = (f16*)(ws);
    f16*   b16  = (f16*)(ws + 50331648);
    f16*   aT   = (f16*)(ws + 100663296);
    f16*   bT   = (f16*)(ws + 150994944);
    f16*   P    = (f16*)(ws + 201326592);
    f16*   PT   = (f16*)(ws + 234881024);
    float* lrow = (float*)(ws + 268435456);
    float* lcol = (float*)(ws + 268566528);

    conv_kernel<<<dim3(H_ / 64, 512 / 64, 2 * B_), 256, 0, stream>>>(
        a, b, a16, b16, aT, bT);
    qk16_kernel<<<dim3(1024, 1, 1), 256, 0, stream>>>(
        a16, b16, ma, mb, temp, P, PT);
    rowsum_kernel<<<dim3(512 / 64, B_, 2), 256, 0, stream>>>(P, PT, lrow, lcol);
    pv16_kernel<<<dim3(3072, 1, 1), 256, 0, stream>>>(
        P, PT, aT, bT, lrow, lcol, out);
}